// Round 1
// baseline (3782.024 us; speedup 1.0000x reference)
//
#include <hip/hip_runtime.h>
#include <hip/hip_bf16.h>
#include <math.h>

#define B_    2
#define T_    2048
#define C_    1024
#define H_    16
#define D_    64
#define R_    4
#define DSTD  60
#define F_    3072
#define BT_   (B_ * T_)

// ---------------------------------------------------------------------------
// GEMM1: fused = x @ W_attn^T, epilogue applies per-(h,d) scale to Q,K
// (Q also gets 1/sqrt(D)=0.125 folded in) and scatters into (B,H,T,D) Q/K/V.
// 64x64 tile, 256 threads, 4x4 micro-tile, K-tile 16.
// ---------------------------------------------------------------------------
__global__ __launch_bounds__(256) void gemm_qkv_kernel(
    const float* __restrict__ x,     // (BT, C)
    const float* __restrict__ Wa,    // (F, C)
    const float* __restrict__ w_std, const float* __restrict__ w_rec,
    const float* __restrict__ skip_std, const float* __restrict__ skip_low,
    float* __restrict__ Q, float* __restrict__ K, float* __restrict__ V)
{
    __shared__ float As[64][17];
    __shared__ float Bs[64][17];

    const int tid  = threadIdx.x;
    const int row0 = blockIdx.x * 64;   // bt tile
    const int col0 = blockIdx.y * 64;   // f tile

    const int lr  = tid >> 2;          // 0..63 : row loaded
    const int lc  = (tid & 3) * 4;     // 0,4,8,12 : col-in-ktile

    const int ty = tid >> 4;           // 0..15 : micro-tile row group
    const int tx = tid & 15;           // 0..15 : micro-tile col group

    float acc[4][4];
#pragma unroll
    for (int i = 0; i < 4; ++i)
#pragma unroll
        for (int j = 0; j < 4; ++j) acc[i][j] = 0.f;

    for (int kt = 0; kt < C_ / 16; ++kt) {
        const int k0 = kt * 16;
        float4 av = *(const float4*)(x  + (size_t)(row0 + lr) * C_ + k0 + lc);
        float4 bv = *(const float4*)(Wa + (size_t)(col0 + lr) * C_ + k0 + lc);
        __syncthreads();
        As[lr][lc + 0] = av.x; As[lr][lc + 1] = av.y;
        As[lr][lc + 2] = av.z; As[lr][lc + 3] = av.w;
        Bs[lr][lc + 0] = bv.x; Bs[lr][lc + 1] = bv.y;
        Bs[lr][lc + 2] = bv.z; Bs[lr][lc + 3] = bv.w;
        __syncthreads();
#pragma unroll
        for (int kk = 0; kk < 16; ++kk) {
            float a_[4], b_[4];
#pragma unroll
            for (int i = 0; i < 4; ++i) a_[i] = As[ty * 4 + i][kk];
#pragma unroll
            for (int j = 0; j < 4; ++j) b_[j] = Bs[tx * 4 + j][kk];
#pragma unroll
            for (int i = 0; i < 4; ++i)
#pragma unroll
                for (int j = 0; j < 4; ++j) acc[i][j] += a_[i] * b_[j];
        }
    }

    // epilogue: scale + scatter into (B,H,T,D)
    const float ss = 1.f / (1.f + __expf(-skip_std[0]));
    const float sl = 1.f / (1.f + __expf(-skip_low[0]));

#pragma unroll
    for (int i = 0; i < 4; ++i) {
        const int rowg = row0 + ty * 4 + i;           // bt
        const int b = rowg >> 11;                      // /T_
        const int t = rowg & (T_ - 1);
#pragma unroll
        for (int j = 0; j < 4; ++j) {
            const int colg  = col0 + tx * 4 + j;       // f
            const int which = colg >> 10;              // 0=q,1=k,2=v
            const int c     = colg & (C_ - 1);
            const int h     = c >> 6;
            const int d     = c & 63;
            const size_t dst = (((size_t)b * H_ + h) * T_ + t) * D_ + d;
            float val = acc[i][j];
            if (which == 2) {
                V[dst] = val;
            } else {
                const float gs = sqrtf(fmaxf(w_std[h] * ss, 1e-8f));
                const float gr = sqrtf(fmaxf(w_rec[h] * sl, 1e-8f));
                float sc = (d < DSTD) ? gs : gr;
                if (which == 0) { Q[dst] = val * sc * 0.125f; }
                else            { K[dst] = val * sc; }
            }
        }
    }
}

// ---------------------------------------------------------------------------
// Flash-style causal attention. Block = 256 threads handles 64 queries of one
// (b,h). Online softmax over 64-key tiles. Epilogue: (1-a)*y + a*V[q].
// Thread (q = tid&63, grp = tid>>6): grp = key-quarter in S-compute,
// d-quarter in PV-accumulate.
// ---------------------------------------------------------------------------
__global__ __launch_bounds__(256) void attn_kernel(
    const float* __restrict__ Q, const float* __restrict__ K,
    const float* __restrict__ V, const float* __restrict__ rwr_alpha,
    float* __restrict__ Y)   // (B,T,C) = (BT, C) row-major
{
    __shared__ float Qs[64][65];
    __shared__ float Ks[64][65];
    __shared__ float Vs[64][65];
    __shared__ float Ss[64][65];

    const int tid = threadIdx.x;
    const int nqt = T_ / 64;                    // 32
    const int qt  = blockIdx.x % nqt;
    const int h   = (blockIdx.x / nqt) % H_;
    const int b   = blockIdx.x / (nqt * H_);

    const float* Qb = Q + (((size_t)b * H_ + h) * T_) * D_;
    const float* Kb = K + (((size_t)b * H_ + h) * T_) * D_;
    const float* Vb = V + (((size_t)b * H_ + h) * T_) * D_;

    // load Q tile (contiguous 4096 floats)
#pragma unroll
    for (int j = 0; j < 4; ++j) {
        const int idx = j * 1024 + tid * 4;
        const int r = idx >> 6, cc = idx & 63;
        float4 v = *(const float4*)(Qb + (size_t)qt * 4096 + idx);
        Qs[r][cc + 0] = v.x; Qs[r][cc + 1] = v.y;
        Qs[r][cc + 2] = v.z; Qs[r][cc + 3] = v.w;
    }

    const int q   = tid & 63;
    const int grp = tid >> 6;       // 0..3
    const int qg  = qt * 64 + q;

    float m = -1e30f, l = 0.f;
    float o[16];
#pragma unroll
    for (int d = 0; d < 16; ++d) o[d] = 0.f;

    for (int kt = 0; kt <= qt; ++kt) {
        __syncthreads();   // previous iter's Ks/Vs/Ss reads done
#pragma unroll
        for (int j = 0; j < 4; ++j) {
            const int idx = j * 1024 + tid * 4;
            const int r = idx >> 6, cc = idx & 63;
            float4 kv = *(const float4*)(Kb + (size_t)kt * 4096 + idx);
            float4 vv = *(const float4*)(Vb + (size_t)kt * 4096 + idx);
            Ks[r][cc + 0] = kv.x; Ks[r][cc + 1] = kv.y;
            Ks[r][cc + 2] = kv.z; Ks[r][cc + 3] = kv.w;
            Vs[r][cc + 0] = vv.x; Vs[r][cc + 1] = vv.y;
            Vs[r][cc + 2] = vv.z; Vs[r][cc + 3] = vv.w;
        }
        __syncthreads();

        // S tile: this thread computes 16 keys for its q
#pragma unroll
        for (int k = 0; k < 16; ++k) {
            const int kk = grp * 16 + k;
            float s = 0.f;
#pragma unroll
            for (int d = 0; d < 64; ++d) s += Qs[q][d] * Ks[kk][d];
            const int kglob = kt * 64 + kk;
            Ss[q][kk] = (kglob <= qg) ? s : -1e30f;
        }
        __syncthreads();

        // online softmax update (m,l replicated across the 4 threads per q)
        float tm = m;
#pragma unroll
        for (int k = 0; k < 64; ++k) tm = fmaxf(tm, Ss[q][k]);
        const float alpha = __expf(m - tm);
        l *= alpha;
#pragma unroll
        for (int d = 0; d < 16; ++d) o[d] *= alpha;
#pragma unroll
        for (int k = 0; k < 64; ++k) {
            const float p = __expf(Ss[q][k] - tm);
            l += p;
#pragma unroll
            for (int d = 0; d < 16; ++d) o[d] += p * Vs[k][grp * 16 + d];
        }
        m = tm;
    }

    // epilogue
    const float a     = fminf(fmaxf(rwr_alpha[h], 0.f), 0.5f);
    const float inv_l = 1.f / l;
    const float* Vq = Vb + (size_t)qg * D_ + grp * 16;
    float* Yp = Y + ((size_t)(b * T_ + qg)) * C_ + h * D_ + grp * 16;
#pragma unroll
    for (int d = 0; d < 16; ++d)
        Yp[d] = (1.f - a) * o[d] * inv_l + a * Vq[d];
}

// ---------------------------------------------------------------------------
// GEMM2: out = Y @ W_proj^T.  Same structure as GEMM1, plain epilogue.
// ---------------------------------------------------------------------------
__global__ __launch_bounds__(256) void gemm_out_kernel(
    const float* __restrict__ Y,    // (BT, C)
    const float* __restrict__ Wp,   // (C, C)
    float* __restrict__ out)        // (BT, C)
{
    __shared__ float As[64][17];
    __shared__ float Bs[64][17];

    const int tid  = threadIdx.x;
    const int row0 = blockIdx.x * 64;
    const int col0 = blockIdx.y * 64;

    const int lr = tid >> 2;
    const int lc = (tid & 3) * 4;
    const int ty = tid >> 4;
    const int tx = tid & 15;

    float acc[4][4];
#pragma unroll
    for (int i = 0; i < 4; ++i)
#pragma unroll
        for (int j = 0; j < 4; ++j) acc[i][j] = 0.f;

    for (int kt = 0; kt < C_ / 16; ++kt) {
        const int k0 = kt * 16;
        float4 av = *(const float4*)(Y  + (size_t)(row0 + lr) * C_ + k0 + lc);
        float4 bv = *(const float4*)(Wp + (size_t)(col0 + lr) * C_ + k0 + lc);
        __syncthreads();
        As[lr][lc + 0] = av.x; As[lr][lc + 1] = av.y;
        As[lr][lc + 2] = av.z; As[lr][lc + 3] = av.w;
        Bs[lr][lc + 0] = bv.x; Bs[lr][lc + 1] = bv.y;
        Bs[lr][lc + 2] = bv.z; Bs[lr][lc + 3] = bv.w;
        __syncthreads();
#pragma unroll
        for (int kk = 0; kk < 16; ++kk) {
            float a_[4], b_[4];
#pragma unroll
            for (int i = 0; i < 4; ++i) a_[i] = As[ty * 4 + i][kk];
#pragma unroll
            for (int j = 0; j < 4; ++j) b_[j] = Bs[tx * 4 + j][kk];
#pragma unroll
            for (int i = 0; i < 4; ++i)
#pragma unroll
                for (int j = 0; j < 4; ++j) acc[i][j] += a_[i] * b_[j];
        }
    }

#pragma unroll
    for (int i = 0; i < 4; ++i) {
        float* op = out + (size_t)(row0 + ty * 4 + i) * C_ + col0 + tx * 4;
        float4 v = make_float4(acc[i][0], acc[i][1], acc[i][2], acc[i][3]);
        *(float4*)op = v;
    }
}

extern "C" void kernel_launch(void* const* d_in, const int* in_sizes, int n_in,
                              void* d_out, int out_size, void* d_ws, size_t ws_size,
                              hipStream_t stream) {
    const float* x        = (const float*)d_in[0];
    const float* W_attn   = (const float*)d_in[1];
    const float* W_proj   = (const float*)d_in[2];
    const float* w_std    = (const float*)d_in[3];
    const float* w_rec    = (const float*)d_in[4];
    const float* skip_std = (const float*)d_in[5];
    const float* skip_low = (const float*)d_in[6];
    const float* rwr      = (const float*)d_in[7];
    float* out = (float*)d_out;

    const size_t per = (size_t)B_ * H_ * T_ * D_;   // 4,194,304 floats
    float* Q = (float*)d_ws;
    float* K = Q + per;
    float* V = K + per;
    float* Y = V + per;                              // 64 MB total fp32

    gemm_qkv_kernel<<<dim3(BT_ / 64, F_ / 64), 256, 0, stream>>>(
        x, W_attn, w_std, w_rec, skip_std, skip_low, Q, K, V);
    attn_kernel<<<dim3(B_ * H_ * (T_ / 64)), 256, 0, stream>>>(Q, K, V, rwr, Y);
    gemm_out_kernel<<<dim3(BT_ / 64, C_ / 64), 256, 0, stream>>>(Y, W_proj, out);
}

// Round 2
// 918.758 us; speedup vs baseline: 4.1165x; 4.1165x over previous
//
#include <hip/hip_runtime.h>
#include <hip/hip_bf16.h>
#include <math.h>

#define B_    2
#define T_    2048
#define C_    1024
#define H_    16
#define D_    64
#define R_    4
#define DSTD  60
#define F_    3072
#define BT_   (B_ * T_)

typedef __bf16 bf16x8 __attribute__((ext_vector_type(8)));
typedef float  f32x4  __attribute__((ext_vector_type(4)));

// column-block XOR swizzle: permutes 8-element blocks within a 64-col row,
// keyed by (row>>1)&7 — keeps b128 reads contiguous, spreads banks for the
// scalar transposed writes.
__device__ __forceinline__ int swz_blk(int row, int blk) {
    return blk ^ ((row >> 1) & 7);
}

// ---------------------------------------------------------------------------
// GEMM1: fused = x @ W_attn^T, epilogue applies per-(h,d) scale to Q,K
// (Q also gets 1/sqrt(D)=0.125 folded in) and scatters into (B,H,T,D) Q/K/V.
// ---------------------------------------------------------------------------
__global__ __launch_bounds__(256) void gemm_qkv_kernel(
    const float* __restrict__ x,     // (BT, C)
    const float* __restrict__ Wa,    // (F, C)
    const float* __restrict__ w_std, const float* __restrict__ w_rec,
    const float* __restrict__ skip_std, const float* __restrict__ skip_low,
    float* __restrict__ Q, float* __restrict__ K, float* __restrict__ V)
{
    __shared__ float As[64][17];
    __shared__ float Bs[64][17];

    const int tid  = threadIdx.x;
    const int row0 = blockIdx.x * 64;   // bt tile
    const int col0 = blockIdx.y * 64;   // f tile

    const int lr  = tid >> 2;
    const int lc  = (tid & 3) * 4;
    const int ty = tid >> 4;
    const int tx = tid & 15;

    float acc[4][4];
#pragma unroll
    for (int i = 0; i < 4; ++i)
#pragma unroll
        for (int j = 0; j < 4; ++j) acc[i][j] = 0.f;

    for (int kt = 0; kt < C_ / 16; ++kt) {
        const int k0 = kt * 16;
        float4 av = *(const float4*)(x  + (size_t)(row0 + lr) * C_ + k0 + lc);
        float4 bv = *(const float4*)(Wa + (size_t)(col0 + lr) * C_ + k0 + lc);
        __syncthreads();
        As[lr][lc + 0] = av.x; As[lr][lc + 1] = av.y;
        As[lr][lc + 2] = av.z; As[lr][lc + 3] = av.w;
        Bs[lr][lc + 0] = bv.x; Bs[lr][lc + 1] = bv.y;
        Bs[lr][lc + 2] = bv.z; Bs[lr][lc + 3] = bv.w;
        __syncthreads();
#pragma unroll
        for (int kk = 0; kk < 16; ++kk) {
            float a_[4], b_[4];
#pragma unroll
            for (int i = 0; i < 4; ++i) a_[i] = As[ty * 4 + i][kk];
#pragma unroll
            for (int j = 0; j < 4; ++j) b_[j] = Bs[tx * 4 + j][kk];
#pragma unroll
            for (int i = 0; i < 4; ++i)
#pragma unroll
                for (int j = 0; j < 4; ++j) acc[i][j] += a_[i] * b_[j];
        }
    }

    const float ss = 1.f / (1.f + __expf(-skip_std[0]));
    const float sl = 1.f / (1.f + __expf(-skip_low[0]));

#pragma unroll
    for (int i = 0; i < 4; ++i) {
        const int rowg = row0 + ty * 4 + i;
        const int b = rowg >> 11;
        const int t = rowg & (T_ - 1);
#pragma unroll
        for (int j = 0; j < 4; ++j) {
            const int colg  = col0 + tx * 4 + j;
            const int which = colg >> 10;
            const int c     = colg & (C_ - 1);
            const int h     = c >> 6;
            const int d     = c & 63;
            const size_t dst = (((size_t)b * H_ + h) * T_ + t) * D_ + d;
            float val = acc[i][j];
            if (which == 2) {
                V[dst] = val;
            } else {
                const float gs = sqrtf(fmaxf(w_std[h] * ss, 1e-8f));
                const float gr = sqrtf(fmaxf(w_rec[h] * sl, 1e-8f));
                float sc = (d < DSTD) ? gs : gr;
                if (which == 0) { Q[dst] = val * sc * 0.125f; }
                else            { K[dst] = val * sc; }
            }
        }
    }
}

// ---------------------------------------------------------------------------
// MFMA flash attention. Block = 256 threads (4 waves) handles 64 queries of
// one (b,h). Wave w owns the 16-query strip [w*16, w*16+16). Per 64-key tile:
//   S strip (16x64) = Q.K^T via 8x mfma_f32_16x16x32_bf16
//   online softmax in C-layout regs (row = quad*4+reg, col = lane&15)
//   P -> LDS (bf16, A-layout round trip, m120 pattern), PV via 8x mfma
// V is staged TRANSPOSED (Vt[d][key]) so PV B-frags are contiguous b128.
// Epilogue fuses (1-a)*y + a*V[q].
// ---------------------------------------------------------------------------
__global__ __launch_bounds__(256) void attn_kernel(
    const float* __restrict__ Q, const float* __restrict__ K,
    const float* __restrict__ V, const float* __restrict__ rwr_alpha,
    float* __restrict__ Y)   // (B,T,C)
{
    __shared__ __align__(16) __bf16 Qs[64][72];
    __shared__ __align__(16) __bf16 Ks[64][72];
    __shared__ __align__(16) __bf16 Vt[64][72];     // Vt[d][key], swizzled cols
    __shared__ __align__(16) __bf16 Ps[4][16][72];  // per-wave P strip, swizzled

    const int tid = threadIdx.x;
    const int nqt = T_ / 64;
    const int qt  = blockIdx.x % nqt;
    const int h   = (blockIdx.x / nqt) % H_;
    const int b   = blockIdx.x / (nqt * H_);

    const float* Qb = Q + (((size_t)b * H_ + h) * T_) * D_;
    const float* Kb = K + (((size_t)b * H_ + h) * T_) * D_;
    const float* Vb = V + (((size_t)b * H_ + h) * T_) * D_;

    const int w    = tid >> 6;
    const int lane = tid & 63;
    const int quad = lane >> 4;
    const int lt   = lane & 15;

    // ---- stage Q tile as bf16 ----
#pragma unroll
    for (int it = 0; it < 4; ++it) {
        const int idx = it * 1024 + tid * 4;
        const int r = idx >> 6, c = idx & 63;
        float4 qv = *(const float4*)(Qb + (size_t)qt * 4096 + idx);
        Qs[r][c + 0] = (__bf16)qv.x; Qs[r][c + 1] = (__bf16)qv.y;
        Qs[r][c + 2] = (__bf16)qv.z; Qs[r][c + 3] = (__bf16)qv.w;
    }
    __syncthreads();

    // A-frags of Q, loop-invariant: A[m=lt][k=quad*8+j], two K-halves
    bf16x8 qf[2];
    qf[0] = *(const bf16x8*)&Qs[w * 16 + lt][quad * 8];
    qf[1] = *(const bf16x8*)&Qs[w * 16 + lt][32 + quad * 8];

    float m[4], l[4];
    f32x4 oacc[4];
#pragma unroll
    for (int r = 0; r < 4; ++r) {
        m[r] = -1e30f; l[r] = 0.f;
#pragma unroll
        for (int n = 0; n < 4; ++n) oacc[n][r] = 0.f;
    }

    for (int kt = 0; kt <= qt; ++kt) {
        __syncthreads();   // previous iter's Ks/Vt reads done
        // ---- stage K (row-major) and V (transposed) as bf16 ----
#pragma unroll
        for (int it = 0; it < 4; ++it) {
            const int idx = it * 1024 + tid * 4;
            const int r = idx >> 6, c = idx & 63;   // r=key, c=d0
            float4 kv = *(const float4*)(Kb + (size_t)kt * 4096 + idx);
            float4 vv = *(const float4*)(Vb + (size_t)kt * 4096 + idx);
            Ks[r][c + 0] = (__bf16)kv.x; Ks[r][c + 1] = (__bf16)kv.y;
            Ks[r][c + 2] = (__bf16)kv.z; Ks[r][c + 3] = (__bf16)kv.w;
            // Vt[d][key] with swizzled column block
            const int kb = r >> 3, ko = r & 7;
            Vt[c + 0][swz_blk(c + 0, kb) * 8 + ko] = (__bf16)vv.x;
            Vt[c + 1][swz_blk(c + 1, kb) * 8 + ko] = (__bf16)vv.y;
            Vt[c + 2][swz_blk(c + 2, kb) * 8 + ko] = (__bf16)vv.z;
            Vt[c + 3][swz_blk(c + 3, kb) * 8 + ko] = (__bf16)vv.w;
        }
        __syncthreads();

        // ---- S = Q.K^T : 4 col-tiles x 2 K-halves ----
        f32x4 sacc[4];
#pragma unroll
        for (int n = 0; n < 4; ++n)
#pragma unroll
            for (int r = 0; r < 4; ++r) sacc[n][r] = 0.f;
#pragma unroll
        for (int kk = 0; kk < 2; ++kk) {
#pragma unroll
            for (int n = 0; n < 4; ++n) {
                bf16x8 bk = *(const bf16x8*)&Ks[n * 16 + lt][kk * 32 + quad * 8];
                sacc[n] = __builtin_amdgcn_mfma_f32_16x16x32_bf16(qf[kk], bk, sacc[n], 0, 0, 0);
            }
        }

        // ---- causal mask on the diagonal tile ----
        if (kt == qt) {
            const int lq = w * 16 + quad * 4;   // + r
#pragma unroll
            for (int n = 0; n < 4; ++n) {
                const int col = n * 16 + lt;
#pragma unroll
                for (int r = 0; r < 4; ++r)
                    if (col > lq + r) sacc[n][r] = -1e30f;
            }
        }

        // ---- online softmax (rows spread over quad*4+reg; cols over 16 lanes) ----
#pragma unroll
        for (int r = 0; r < 4; ++r) {
            float tm = fmaxf(fmaxf(sacc[0][r], sacc[1][r]), fmaxf(sacc[2][r], sacc[3][r]));
            tm = fmaxf(tm, __shfl_xor(tm, 1));
            tm = fmaxf(tm, __shfl_xor(tm, 2));
            tm = fmaxf(tm, __shfl_xor(tm, 4));
            tm = fmaxf(tm, __shfl_xor(tm, 8));
            const float mn = fmaxf(m[r], tm);
            const float al = __expf(m[r] - mn);
            m[r] = mn;
            l[r] *= al;
#pragma unroll
            for (int n = 0; n < 4; ++n) oacc[n][r] *= al;
            float rs = 0.f;
            const int prow = quad * 4 + r;
#pragma unroll
            for (int n = 0; n < 4; ++n) {
                const float p = __expf(sacc[n][r] - mn);
                rs += p;
                const int col = n * 16 + lt;
                Ps[w][prow][swz_blk(prow, col >> 3) * 8 + (col & 7)] = (__bf16)p;
            }
            rs += __shfl_xor(rs, 1);
            rs += __shfl_xor(rs, 2);
            rs += __shfl_xor(rs, 4);
            rs += __shfl_xor(rs, 8);
            l[r] += rs;
        }

        // ---- PV: A = P (LDS round-trip), B = V^T-contiguous (Vt rows) ----
        // same-wave DS ordering guarantees the Ps writes above are visible
#pragma unroll
        for (int kk = 0; kk < 2; ++kk) {
            bf16x8 ap = *(const bf16x8*)&Ps[w][lt][swz_blk(lt, kk * 4 + quad) * 8];
#pragma unroll
            for (int nd = 0; nd < 4; ++nd) {
                const int drow = nd * 16 + lt;
                bf16x8 bv = *(const bf16x8*)&Vt[drow][swz_blk(drow, kk * 4 + quad) * 8];
                oacc[nd] = __builtin_amdgcn_mfma_f32_16x16x32_bf16(ap, bv, oacc[nd], 0, 0, 0);
            }
        }
    }

    // ---- epilogue: normalize + (1-a)*y + a*V[q] ----
    const float a = fminf(fmaxf(rwr_alpha[h], 0.f), 0.5f);
#pragma unroll
    for (int r = 0; r < 4; ++r) {
        const float inv = 1.f / l[r];
        const int qg = qt * 64 + w * 16 + quad * 4 + r;
        const float* vp = Vb + (size_t)qg * D_;
        float* yp = Y + ((size_t)(b * T_ + qg)) * C_ + h * D_;
#pragma unroll
        for (int nd = 0; nd < 4; ++nd) {
            const int d = nd * 16 + lt;
            yp[d] = (1.f - a) * oacc[nd][r] * inv + a * vp[d];
        }
    }
}

// ---------------------------------------------------------------------------
// GEMM2: out = Y @ W_proj^T.
// ---------------------------------------------------------------------------
__global__ __launch_bounds__(256) void gemm_out_kernel(
    const float* __restrict__ Y,    // (BT, C)
    const float* __restrict__ Wp,   // (C, C)
    float* __restrict__ out)        // (BT, C)
{
    __shared__ float As[64][17];
    __shared__ float Bs[64][17];

    const int tid  = threadIdx.x;
    const int row0 = blockIdx.x * 64;
    const int col0 = blockIdx.y * 64;

    const int lr = tid >> 2;
    const int lc = (tid & 3) * 4;
    const int ty = tid >> 4;
    const int tx = tid & 15;

    float acc[4][4];
#pragma unroll
    for (int i = 0; i < 4; ++i)
#pragma unroll
        for (int j = 0; j < 4; ++j) acc[i][j] = 0.f;

    for (int kt = 0; kt < C_ / 16; ++kt) {
        const int k0 = kt * 16;
        float4 av = *(const float4*)(Y  + (size_t)(row0 + lr) * C_ + k0 + lc);
        float4 bv = *(const float4*)(Wp + (size_t)(col0 + lr) * C_ + k0 + lc);
        __syncthreads();
        As[lr][lc + 0] = av.x; As[lr][lc + 1] = av.y;
        As[lr][lc + 2] = av.z; As[lr][lc + 3] = av.w;
        Bs[lr][lc + 0] = bv.x; Bs[lr][lc + 1] = bv.y;
        Bs[lr][lc + 2] = bv.z; Bs[lr][lc + 3] = bv.w;
        __syncthreads();
#pragma unroll
        for (int kk = 0; kk < 16; ++kk) {
            float a_[4], b_[4];
#pragma unroll
            for (int i = 0; i < 4; ++i) a_[i] = As[ty * 4 + i][kk];
#pragma unroll
            for (int j = 0; j < 4; ++j) b_[j] = Bs[tx * 4 + j][kk];
#pragma unroll
            for (int i = 0; i < 4; ++i)
#pragma unroll
                for (int j = 0; j < 4; ++j) acc[i][j] += a_[i] * b_[j];
        }
    }

#pragma unroll
    for (int i = 0; i < 4; ++i) {
        float* op = out + (size_t)(row0 + ty * 4 + i) * C_ + col0 + tx * 4;
        float4 v = make_float4(acc[i][0], acc[i][1], acc[i][2], acc[i][3]);
        *(float4*)op = v;
    }
}

extern "C" void kernel_launch(void* const* d_in, const int* in_sizes, int n_in,
                              void* d_out, int out_size, void* d_ws, size_t ws_size,
                              hipStream_t stream) {
    const float* x        = (const float*)d_in[0];
    const float* W_attn   = (const float*)d_in[1];
    const float* W_proj   = (const float*)d_in[2];
    const float* w_std    = (const float*)d_in[3];
    const float* w_rec    = (const float*)d_in[4];
    const float* skip_std = (const float*)d_in[5];
    const float* skip_low = (const float*)d_in[6];
    const float* rwr      = (const float*)d_in[7];
    float* out = (float*)d_out;

    const size_t per = (size_t)B_ * H_ * T_ * D_;
    float* Q = (float*)d_ws;
    float* K = Q + per;
    float* V = K + per;
    float* Y = V + per;

    gemm_qkv_kernel<<<dim3(BT_ / 64, F_ / 64), 256, 0, stream>>>(
        x, W_attn, w_std, w_rec, skip_std, skip_low, Q, K, V);
    attn_kernel<<<dim3(B_ * H_ * (T_ / 64)), 256, 0, stream>>>(Q, K, V, rwr, Y);
    gemm_out_kernel<<<dim3(BT_ / 64, C_ / 64), 256, 0, stream>>>(Y, W_proj, out);
}

// Round 3
// 292.995 us; speedup vs baseline: 12.9081x; 3.1357x over previous
//
#include <hip/hip_runtime.h>
#include <hip/hip_bf16.h>
#include <math.h>
#include <stdint.h>

#define B_    2
#define T_    2048
#define C_    1024
#define H_    16
#define D_    64
#define R_    4
#define DSTD  60
#define F_    3072
#define BT_   (B_ * T_)

typedef __bf16 bf16x8 __attribute__((ext_vector_type(8)));
typedef __bf16 bf16x4 __attribute__((ext_vector_type(4)));
typedef float  f32x4  __attribute__((ext_vector_type(4)));

__device__ __forceinline__ int swz_blk(int row, int blk) {
    return blk ^ ((row >> 1) & 7);
}

// async global->LDS, 16B per lane. LDS dest MUST be wave-uniform base + lane*16.
__device__ __forceinline__ void gload_lds16(const void* g, void* l) {
    __builtin_amdgcn_global_load_lds(
        (const __attribute__((address_space(1))) uint32_t*)g,
        (__attribute__((address_space(3))) uint32_t*)l, 16, 0, 0);
}

// ---------------------------------------------------------------------------
// fp32 -> bf16 cast, memory-bound
// ---------------------------------------------------------------------------
__global__ __launch_bounds__(256) void cast_kernel(
    const float* __restrict__ in, __bf16* __restrict__ outp, int n4)
{
    int i = blockIdx.x * 256 + threadIdx.x;
    if (i < n4) {
        float4 v = ((const float4*)in)[i];
        bf16x4 o;
        o[0] = (__bf16)v.x; o[1] = (__bf16)v.y;
        o[2] = (__bf16)v.z; o[3] = (__bf16)v.w;
        ((bf16x4*)outp)[i] = o;
    }
}

// ---------------------------------------------------------------------------
// m97-style bf16 MFMA GEMM: out = A(M,K) @ B(N,K)^T. 128x128 tile, 256 thr
// (4 waves, each 64x64 via 4x4 of 16x16x32), BK=32, global_load_lds w16.
// GEMM1 epilogue: scale q/k, scatter bf16 into (B,H,T,D) Q/K/V.
// ---------------------------------------------------------------------------
__global__ __launch_bounds__(256) void gemm_qkv_kernel(
    const __bf16* __restrict__ A,    // x   (BT, C) bf16
    const __bf16* __restrict__ Bw,   // Wa  (F,  C) bf16
    const float* __restrict__ w_std, const float* __restrict__ w_rec,
    const float* __restrict__ skip_std, const float* __restrict__ skip_low,
    __bf16* __restrict__ Q, __bf16* __restrict__ K, __bf16* __restrict__ V)
{
    __shared__ __bf16 As[128 * 32];
    __shared__ __bf16 Bs[128 * 32];

    const int tid  = threadIdx.x;
    const int row0 = blockIdx.x * 128;
    const int col0 = blockIdx.y * 128;

    const int w    = tid >> 6;
    const int lane = tid & 63;
    const int quad = lane >> 4;
    const int lt   = lane & 15;
    const int wm   = w >> 1;        // 0..1
    const int wn   = w & 1;         // 0..1

    const int lrow = tid >> 2;      // 0..63  (staging row within 64-row round)
    const int lcol = (tid & 3) * 8; // 0,8,16,24

    f32x4 acc[4][4];
#pragma unroll
    for (int i = 0; i < 4; ++i)
#pragma unroll
        for (int j = 0; j < 4; ++j)
#pragma unroll
            for (int r = 0; r < 4; ++r) acc[i][j][r] = 0.f;

    for (int kt = 0; kt < C_ / 32; ++kt) {
        const int k0 = kt * 32;
        __syncthreads();   // previous iter's ds_reads done
#pragma unroll
        for (int rr = 0; rr < 2; ++rr) {
            gload_lds16(A  + (size_t)(row0 + rr * 64 + lrow) * C_ + k0 + lcol,
                        As + rr * 2048 + tid * 8);
            gload_lds16(Bw + (size_t)(col0 + rr * 64 + lrow) * C_ + k0 + lcol,
                        Bs + rr * 2048 + tid * 8);
        }
        __syncthreads();   // drains vmcnt -> LDS tiles ready

        bf16x8 af[4], bf[4];
#pragma unroll
        for (int i = 0; i < 4; ++i)
            af[i] = *(const bf16x8*)&As[(wm * 64 + i * 16 + lt) * 32 + quad * 8];
#pragma unroll
        for (int j = 0; j < 4; ++j)
            bf[j] = *(const bf16x8*)&Bs[(wn * 64 + j * 16 + lt) * 32 + quad * 8];
#pragma unroll
        for (int i = 0; i < 4; ++i)
#pragma unroll
            for (int j = 0; j < 4; ++j)
                acc[i][j] = __builtin_amdgcn_mfma_f32_16x16x32_bf16(af[i], bf[j], acc[i][j], 0, 0, 0);
    }

    // ---- epilogue: h is uniform per (block, wn); d = j*16+lt ----
    const int colbase = col0 + wn * 64;          // multiple of 64
    const int which   = colbase >> 10;           // 0=q 1=k 2=v (tile never straddles)
    const int h       = (colbase & (C_ - 1)) >> 6;

    const float ss = 1.f / (1.f + __expf(-skip_std[0]));
    const float sl = 1.f / (1.f + __expf(-skip_low[0]));
    const float gs = sqrtf(fmaxf(w_std[h] * ss, 1e-8f));
    const float gr = sqrtf(fmaxf(w_rec[h] * sl, 1e-8f));

    __bf16* dstM = (which == 0) ? Q : (which == 1) ? K : V;

#pragma unroll
    for (int i = 0; i < 4; ++i) {
#pragma unroll
        for (int r = 0; r < 4; ++r) {
            const int row = row0 + wm * 64 + i * 16 + quad * 4 + r;   // bt
            const int b = row >> 11;
            const int t = row & (T_ - 1);
            __bf16* dp = dstM + (((size_t)b * H_ + h) * T_ + t) * D_;
#pragma unroll
            for (int j = 0; j < 4; ++j) {
                const int d = j * 16 + lt;
                float val = acc[i][j][r];
                if (which == 0)      val *= ((d < DSTD) ? gs : gr) * 0.125f;
                else if (which == 1) val *= (d < DSTD) ? gs : gr;
                dp[d] = (__bf16)val;
            }
        }
    }
}

// ---------------------------------------------------------------------------
// GEMM2: out = Y(BT,C) @ Wp(C,C)^T, fp32 out. Same m97 structure.
// ---------------------------------------------------------------------------
__global__ __launch_bounds__(256) void gemm_out_kernel(
    const __bf16* __restrict__ A,    // Y  (BT, C) bf16
    const __bf16* __restrict__ Bw,   // Wp (C,  C) bf16
    float* __restrict__ out)
{
    __shared__ __bf16 As[128 * 32];
    __shared__ __bf16 Bs[128 * 32];

    const int tid  = threadIdx.x;
    const int row0 = blockIdx.x * 128;
    const int col0 = blockIdx.y * 128;

    const int w    = tid >> 6;
    const int lane = tid & 63;
    const int quad = lane >> 4;
    const int lt   = lane & 15;
    const int wm   = w >> 1;
    const int wn   = w & 1;

    const int lrow = tid >> 2;
    const int lcol = (tid & 3) * 8;

    f32x4 acc[4][4];
#pragma unroll
    for (int i = 0; i < 4; ++i)
#pragma unroll
        for (int j = 0; j < 4; ++j)
#pragma unroll
            for (int r = 0; r < 4; ++r) acc[i][j][r] = 0.f;

    for (int kt = 0; kt < C_ / 32; ++kt) {
        const int k0 = kt * 32;
        __syncthreads();
#pragma unroll
        for (int rr = 0; rr < 2; ++rr) {
            gload_lds16(A  + (size_t)(row0 + rr * 64 + lrow) * C_ + k0 + lcol,
                        As + rr * 2048 + tid * 8);
            gload_lds16(Bw + (size_t)(col0 + rr * 64 + lrow) * C_ + k0 + lcol,
                        Bs + rr * 2048 + tid * 8);
        }
        __syncthreads();

        bf16x8 af[4], bf[4];
#pragma unroll
        for (int i = 0; i < 4; ++i)
            af[i] = *(const bf16x8*)&As[(wm * 64 + i * 16 + lt) * 32 + quad * 8];
#pragma unroll
        for (int j = 0; j < 4; ++j)
            bf[j] = *(const bf16x8*)&Bs[(wn * 64 + j * 16 + lt) * 32 + quad * 8];
#pragma unroll
        for (int i = 0; i < 4; ++i)
#pragma unroll
            for (int j = 0; j < 4; ++j)
                acc[i][j] = __builtin_amdgcn_mfma_f32_16x16x32_bf16(af[i], bf[j], acc[i][j], 0, 0, 0);
    }

#pragma unroll
    for (int i = 0; i < 4; ++i)
#pragma unroll
        for (int r = 0; r < 4; ++r) {
            const int row = row0 + wm * 64 + i * 16 + quad * 4 + r;
            float* op = out + (size_t)row * C_ + col0 + wn * 64 + lt;
#pragma unroll
            for (int j = 0; j < 4; ++j)
                op[j * 16] = acc[i][j][r];
        }
}

// ---------------------------------------------------------------------------
// MFMA flash attention (bf16 Q/K/V in, bf16 Y out). Unchanged structure.
// ---------------------------------------------------------------------------
__global__ __launch_bounds__(256) void attn_kernel(
    const __bf16* __restrict__ Q, const __bf16* __restrict__ K,
    const __bf16* __restrict__ V, const float* __restrict__ rwr_alpha,
    __bf16* __restrict__ Y)   // (B,T,C) bf16
{
    __shared__ __align__(16) __bf16 Qs[64][72];
    __shared__ __align__(16) __bf16 Ks[64][72];
    __shared__ __align__(16) __bf16 Vt[64][72];
    __shared__ __align__(16) __bf16 Ps[4][16][72];

    const int tid = threadIdx.x;
    const int nqt = T_ / 64;
    const int qt  = blockIdx.x % nqt;
    const int h   = (blockIdx.x / nqt) % H_;
    const int b   = blockIdx.x / (nqt * H_);

    const __bf16* Qb = Q + (((size_t)b * H_ + h) * T_) * D_;
    const __bf16* Kb = K + (((size_t)b * H_ + h) * T_) * D_;
    const __bf16* Vb = V + (((size_t)b * H_ + h) * T_) * D_;

    const int w    = tid >> 6;
    const int lane = tid & 63;
    const int quad = lane >> 4;
    const int lt   = lane & 15;

    const int sr = tid >> 2;             // staging row
    const int sc = (tid & 3) * 16;       // staging col0

    // ---- stage Q tile ----
    {
        const __bf16* src = Qb + (size_t)qt * 4096 + sr * 64 + sc;
        *(bf16x8*)&Qs[sr][sc]     = *(const bf16x8*)(src);
        *(bf16x8*)&Qs[sr][sc + 8] = *(const bf16x8*)(src + 8);
    }
    __syncthreads();

    bf16x8 qf[2];
    qf[0] = *(const bf16x8*)&Qs[w * 16 + lt][quad * 8];
    qf[1] = *(const bf16x8*)&Qs[w * 16 + lt][32 + quad * 8];

    float m[4], l[4];
    f32x4 oacc[4];
#pragma unroll
    for (int r = 0; r < 4; ++r) {
        m[r] = -1e30f; l[r] = 0.f;
#pragma unroll
        for (int n = 0; n < 4; ++n) oacc[n][r] = 0.f;
    }

    for (int kt = 0; kt <= qt; ++kt) {
        __syncthreads();
        {
            const __bf16* ks = Kb + (size_t)kt * 4096 + sr * 64 + sc;
            const __bf16* vs = Vb + (size_t)kt * 4096 + sr * 64 + sc;
            bf16x8 k1 = *(const bf16x8*)(ks);
            bf16x8 k2 = *(const bf16x8*)(ks + 8);
            bf16x8 v1 = *(const bf16x8*)(vs);
            bf16x8 v2 = *(const bf16x8*)(vs + 8);
            *(bf16x8*)&Ks[sr][sc]     = k1;
            *(bf16x8*)&Ks[sr][sc + 8] = k2;
            const int kb = sr >> 3, ko = sr & 7;
#pragma unroll
            for (int u = 0; u < 8; ++u) {
                Vt[sc + u    ][swz_blk(sc + u,     kb) * 8 + ko] = v1[u];
                Vt[sc + 8 + u][swz_blk(sc + 8 + u, kb) * 8 + ko] = v2[u];
            }
        }
        __syncthreads();

        f32x4 sacc[4];
#pragma unroll
        for (int n = 0; n < 4; ++n)
#pragma unroll
            for (int r = 0; r < 4; ++r) sacc[n][r] = 0.f;
#pragma unroll
        for (int kk = 0; kk < 2; ++kk) {
#pragma unroll
            for (int n = 0; n < 4; ++n) {
                bf16x8 bk = *(const bf16x8*)&Ks[n * 16 + lt][kk * 32 + quad * 8];
                sacc[n] = __builtin_amdgcn_mfma_f32_16x16x32_bf16(qf[kk], bk, sacc[n], 0, 0, 0);
            }
        }

        if (kt == qt) {
            const int lq = w * 16 + quad * 4;
#pragma unroll
            for (int n = 0; n < 4; ++n) {
                const int col = n * 16 + lt;
#pragma unroll
                for (int r = 0; r < 4; ++r)
                    if (col > lq + r) sacc[n][r] = -1e30f;
            }
        }

#pragma unroll
        for (int r = 0; r < 4; ++r) {
            float tm = fmaxf(fmaxf(sacc[0][r], sacc[1][r]), fmaxf(sacc[2][r], sacc[3][r]));
            tm = fmaxf(tm, __shfl_xor(tm, 1));
            tm = fmaxf(tm, __shfl_xor(tm, 2));
            tm = fmaxf(tm, __shfl_xor(tm, 4));
            tm = fmaxf(tm, __shfl_xor(tm, 8));
            const float mn = fmaxf(m[r], tm);
            const float al = __expf(m[r] - mn);
            m[r] = mn;
            l[r] *= al;
#pragma unroll
            for (int n = 0; n < 4; ++n) oacc[n][r] *= al;
            float rs = 0.f;
            const int prow = quad * 4 + r;
#pragma unroll
            for (int n = 0; n < 4; ++n) {
                const float p = __expf(sacc[n][r] - mn);
                rs += p;
                const int col = n * 16 + lt;
                Ps[w][prow][swz_blk(prow, col >> 3) * 8 + (col & 7)] = (__bf16)p;
            }
            rs += __shfl_xor(rs, 1);
            rs += __shfl_xor(rs, 2);
            rs += __shfl_xor(rs, 4);
            rs += __shfl_xor(rs, 8);
            l[r] += rs;
        }

#pragma unroll
        for (int kk = 0; kk < 2; ++kk) {
            bf16x8 ap = *(const bf16x8*)&Ps[w][lt][swz_blk(lt, kk * 4 + quad) * 8];
#pragma unroll
            for (int nd = 0; nd < 4; ++nd) {
                const int drow = nd * 16 + lt;
                bf16x8 bv = *(const bf16x8*)&Vt[drow][swz_blk(drow, kk * 4 + quad) * 8];
                oacc[nd] = __builtin_amdgcn_mfma_f32_16x16x32_bf16(ap, bv, oacc[nd], 0, 0, 0);
            }
        }
    }

    const float a = fminf(fmaxf(rwr_alpha[h], 0.f), 0.5f);
#pragma unroll
    for (int r = 0; r < 4; ++r) {
        const float inv = 1.f / l[r];
        const int qg = qt * 64 + w * 16 + quad * 4 + r;
        const __bf16* vp = Vb + (size_t)qg * D_;
        __bf16* yp = Y + ((size_t)(b * T_ + qg)) * C_ + h * D_;
#pragma unroll
        for (int nd = 0; nd < 4; ++nd) {
            const int d = nd * 16 + lt;
            yp[d] = (__bf16)((1.f - a) * oacc[nd][r] * inv + a * (float)vp[d]);
        }
    }
}

extern "C" void kernel_launch(void* const* d_in, const int* in_sizes, int n_in,
                              void* d_out, int out_size, void* d_ws, size_t ws_size,
                              hipStream_t stream) {
    const float* x        = (const float*)d_in[0];
    const float* W_attn   = (const float*)d_in[1];
    const float* W_proj   = (const float*)d_in[2];
    const float* w_std    = (const float*)d_in[3];
    const float* w_rec    = (const float*)d_in[4];
    const float* skip_std = (const float*)d_in[5];
    const float* skip_low = (const float*)d_in[6];
    const float* rwr      = (const float*)d_in[7];
    float* out = (float*)d_out;

    const size_t nX  = (size_t)BT_ * C_;     // 4,194,304
    const size_t nWa = (size_t)F_ * C_;      // 3,145,728
    const size_t nWp = (size_t)C_ * C_;      // 1,048,576
    const size_t per = (size_t)B_ * H_ * T_ * D_;

    __bf16* xb  = (__bf16*)d_ws;
    __bf16* Wab = xb  + nX;
    __bf16* Wpb = Wab + nWa;
    __bf16* Qb  = Wpb + nWp;
    __bf16* Kb  = Qb  + per;
    __bf16* Vb  = Kb  + per;
    __bf16* Yb  = Vb  + per;          // total ~50 MB bf16

    cast_kernel<<<dim3((nX  / 4 + 255) / 256), 256, 0, stream>>>(x,      xb,  nX  / 4);
    cast_kernel<<<dim3((nWa / 4 + 255) / 256), 256, 0, stream>>>(W_attn, Wab, nWa / 4);
    cast_kernel<<<dim3((nWp / 4 + 255) / 256), 256, 0, stream>>>(W_proj, Wpb, nWp / 4);

    gemm_qkv_kernel<<<dim3(BT_ / 128, F_ / 128), 256, 0, stream>>>(
        xb, Wab, w_std, w_rec, skip_std, skip_low, Qb, Kb, Vb);
    attn_kernel<<<dim3(B_ * H_ * (T_ / 64)), 256, 0, stream>>>(Qb, Kb, Vb, rwr, Yb);
    gemm_out_kernel<<<dim3(BT_ / 128, C_ / 128), 256, 0, stream>>>(Yb, Wpb, out);
}

// Round 4
// 212.698 us; speedup vs baseline: 17.7812x; 1.3775x over previous
//
#include <hip/hip_runtime.h>
#include <hip/hip_bf16.h>
#include <math.h>
#include <stdint.h>

#define B_    2
#define T_    2048
#define C_    1024
#define H_    16
#define D_    64
#define R_    4
#define DSTD  60
#define F_    3072
#define BT_   (B_ * T_)

typedef __bf16 bf16x8 __attribute__((ext_vector_type(8)));
typedef __bf16 bf16x4 __attribute__((ext_vector_type(4)));
typedef float  f32x4  __attribute__((ext_vector_type(4)));

__device__ __forceinline__ int swz_blk(int row, int blk) {
    return blk ^ ((row >> 1) & 7);
}

// async global->LDS, 16B per lane. LDS dest MUST be wave-uniform base + lane*16.
__device__ __forceinline__ void gload_lds16(const void* g, void* l) {
    __builtin_amdgcn_global_load_lds(
        (const __attribute__((address_space(1))) uint32_t*)g,
        (__attribute__((address_space(3))) uint32_t*)l, 16, 0, 0);
}

// ---------------------------------------------------------------------------
// fp32 -> bf16 cast, memory-bound
// ---------------------------------------------------------------------------
__global__ __launch_bounds__(256) void cast_kernel(
    const float* __restrict__ in, __bf16* __restrict__ outp, int n4)
{
    int i = blockIdx.x * 256 + threadIdx.x;
    if (i < n4) {
        float4 v = ((const float4*)in)[i];
        bf16x4 o;
        o[0] = (__bf16)v.x; o[1] = (__bf16)v.y;
        o[2] = (__bf16)v.z; o[3] = (__bf16)v.w;
        ((bf16x4*)outp)[i] = o;
    }
}

// ---------------------------------------------------------------------------
// m97-style bf16 MFMA GEMM: out = A(M,K) @ B(N,K)^T. 128x128 tile, 256 thr.
// GEMM1 epilogue: scale q/k, scatter bf16 into (B,H,T,D) Q/K/V.
// ---------------------------------------------------------------------------
__global__ __launch_bounds__(256) void gemm_qkv_kernel(
    const __bf16* __restrict__ A,    // x   (BT, C) bf16
    const __bf16* __restrict__ Bw,   // Wa  (F,  C) bf16
    const float* __restrict__ w_std, const float* __restrict__ w_rec,
    const float* __restrict__ skip_std, const float* __restrict__ skip_low,
    __bf16* __restrict__ Q, __bf16* __restrict__ K, __bf16* __restrict__ V)
{
    __shared__ __bf16 As[128 * 32];
    __shared__ __bf16 Bs[128 * 32];

    const int tid  = threadIdx.x;
    const int row0 = blockIdx.x * 128;
    const int col0 = blockIdx.y * 128;

    const int w    = tid >> 6;
    const int lane = tid & 63;
    const int quad = lane >> 4;
    const int lt   = lane & 15;
    const int wm   = w >> 1;
    const int wn   = w & 1;

    const int lrow = tid >> 2;
    const int lcol = (tid & 3) * 8;

    f32x4 acc[4][4];
#pragma unroll
    for (int i = 0; i < 4; ++i)
#pragma unroll
        for (int j = 0; j < 4; ++j)
#pragma unroll
            for (int r = 0; r < 4; ++r) acc[i][j][r] = 0.f;

    for (int kt = 0; kt < C_ / 32; ++kt) {
        const int k0 = kt * 32;
        __syncthreads();
#pragma unroll
        for (int rr = 0; rr < 2; ++rr) {
            gload_lds16(A  + (size_t)(row0 + rr * 64 + lrow) * C_ + k0 + lcol,
                        As + rr * 2048 + tid * 8);
            gload_lds16(Bw + (size_t)(col0 + rr * 64 + lrow) * C_ + k0 + lcol,
                        Bs + rr * 2048 + tid * 8);
        }
        __syncthreads();

        bf16x8 af[4], bf[4];
#pragma unroll
        for (int i = 0; i < 4; ++i)
            af[i] = *(const bf16x8*)&As[(wm * 64 + i * 16 + lt) * 32 + quad * 8];
#pragma unroll
        for (int j = 0; j < 4; ++j)
            bf[j] = *(const bf16x8*)&Bs[(wn * 64 + j * 16 + lt) * 32 + quad * 8];
#pragma unroll
        for (int i = 0; i < 4; ++i)
#pragma unroll
            for (int j = 0; j < 4; ++j)
                acc[i][j] = __builtin_amdgcn_mfma_f32_16x16x32_bf16(af[i], bf[j], acc[i][j], 0, 0, 0);
    }

    const int colbase = col0 + wn * 64;
    const int which   = colbase >> 10;
    const int h       = (colbase & (C_ - 1)) >> 6;

    const float ss = 1.f / (1.f + __expf(-skip_std[0]));
    const float sl = 1.f / (1.f + __expf(-skip_low[0]));
    const float gs = sqrtf(fmaxf(w_std[h] * ss, 1e-8f));
    const float gr = sqrtf(fmaxf(w_rec[h] * sl, 1e-8f));

    __bf16* dstM = (which == 0) ? Q : (which == 1) ? K : V;

#pragma unroll
    for (int i = 0; i < 4; ++i) {
#pragma unroll
        for (int r = 0; r < 4; ++r) {
            const int row = row0 + wm * 64 + i * 16 + quad * 4 + r;
            const int b = row >> 11;
            const int t = row & (T_ - 1);
            __bf16* dp = dstM + (((size_t)b * H_ + h) * T_ + t) * D_;
#pragma unroll
            for (int j = 0; j < 4; ++j) {
                const int d = j * 16 + lt;
                float val = acc[i][j][r];
                if (which == 0)      val *= ((d < DSTD) ? gs : gr) * 0.125f;
                else if (which == 1) val *= (d < DSTD) ? gs : gr;
                dp[d] = (__bf16)val;
            }
        }
    }
}

// ---------------------------------------------------------------------------
// GEMM2: out = Y(BT,C) @ Wp(C,C)^T, fp32 out.
// ---------------------------------------------------------------------------
__global__ __launch_bounds__(256) void gemm_out_kernel(
    const __bf16* __restrict__ A,
    const __bf16* __restrict__ Bw,
    float* __restrict__ out)
{
    __shared__ __bf16 As[128 * 32];
    __shared__ __bf16 Bs[128 * 32];

    const int tid  = threadIdx.x;
    const int row0 = blockIdx.x * 128;
    const int col0 = blockIdx.y * 128;

    const int w    = tid >> 6;
    const int lane = tid & 63;
    const int quad = lane >> 4;
    const int lt   = lane & 15;
    const int wm   = w >> 1;
    const int wn   = w & 1;

    const int lrow = tid >> 2;
    const int lcol = (tid & 3) * 8;

    f32x4 acc[4][4];
#pragma unroll
    for (int i = 0; i < 4; ++i)
#pragma unroll
        for (int j = 0; j < 4; ++j)
#pragma unroll
            for (int r = 0; r < 4; ++r) acc[i][j][r] = 0.f;

    for (int kt = 0; kt < C_ / 32; ++kt) {
        const int k0 = kt * 32;
        __syncthreads();
#pragma unroll
        for (int rr = 0; rr < 2; ++rr) {
            gload_lds16(A  + (size_t)(row0 + rr * 64 + lrow) * C_ + k0 + lcol,
                        As + rr * 2048 + tid * 8);
            gload_lds16(Bw + (size_t)(col0 + rr * 64 + lrow) * C_ + k0 + lcol,
                        Bs + rr * 2048 + tid * 8);
        }
        __syncthreads();

        bf16x8 af[4], bf[4];
#pragma unroll
        for (int i = 0; i < 4; ++i)
            af[i] = *(const bf16x8*)&As[(wm * 64 + i * 16 + lt) * 32 + quad * 8];
#pragma unroll
        for (int j = 0; j < 4; ++j)
            bf[j] = *(const bf16x8*)&Bs[(wn * 64 + j * 16 + lt) * 32 + quad * 8];
#pragma unroll
        for (int i = 0; i < 4; ++i)
#pragma unroll
            for (int j = 0; j < 4; ++j)
                acc[i][j] = __builtin_amdgcn_mfma_f32_16x16x32_bf16(af[i], bf[j], acc[i][j], 0, 0, 0);
    }

#pragma unroll
    for (int i = 0; i < 4; ++i)
#pragma unroll
        for (int r = 0; r < 4; ++r) {
            const int row = row0 + wm * 64 + i * 16 + quad * 4 + r;
            float* op = out + (size_t)row * C_ + col0 + wn * 64 + lt;
#pragma unroll
            for (int j = 0; j < 4; ++j)
                op[j * 16] = acc[i][j][r];
        }
}

// ---------------------------------------------------------------------------
// MFMA flash attention, R3: LPT dispatch (qt descending), double-buffered
// K/V LDS with ONE barrier per iteration (prefetch into regs overlaps
// compute), Q frags direct from global (no Qs), strip-wide softmax max with
// wave-uniform rescale skip.
// ---------------------------------------------------------------------------
__global__ __launch_bounds__(256) void attn_kernel(
    const __bf16* __restrict__ Q, const __bf16* __restrict__ K,
    const __bf16* __restrict__ V, const float* __restrict__ rwr_alpha,
    __bf16* __restrict__ Y)   // (B,T,C) bf16
{
    __shared__ __align__(16) __bf16 Ks[2][64][72];
    __shared__ __align__(16) __bf16 Vt[2][64][72];
    __shared__ __align__(16) __bf16 Ps[4][16][72];

    const int tid = threadIdx.x;
    const int nqt = T_ / 64;                       // 32
    // LPT: qt descending with blockIdx so heavy blocks dispatch first
    const int bh  = blockIdx.x & 31;               // b*H + h
    const int qt  = nqt - 1 - (blockIdx.x >> 5);
    const int h   = bh & (H_ - 1);
    const int b   = bh >> 4;

    const __bf16* Qb = Q + (((size_t)b * H_ + h) * T_) * D_;
    const __bf16* Kb = K + (((size_t)b * H_ + h) * T_) * D_;
    const __bf16* Vb = V + (((size_t)b * H_ + h) * T_) * D_;

    const int w    = tid >> 6;
    const int lane = tid & 63;
    const int quad = lane >> 4;
    const int lt   = lane & 15;

    const int sr = tid >> 2;             // staging row (key)
    const int sc = (tid & 3) * 16;       // staging col0 (d)
    const int kb = sr >> 3, ko = sr & 7; // transposed-write block/offset

    // ---- Q A-frags direct from global ----
    const __bf16* qrow = Qb + (size_t)(qt * 64 + w * 16 + lt) * D_;
    bf16x8 qf[2];
    qf[0] = *(const bf16x8*)(qrow + quad * 8);
    qf[1] = *(const bf16x8*)(qrow + 32 + quad * 8);

    // ---- stage tile 0 into buffer 0 ----
    {
        const __bf16* ks = Kb + sr * 64 + sc;
        const __bf16* vs = Vb + sr * 64 + sc;
        bf16x8 k1 = *(const bf16x8*)(ks);
        bf16x8 k2 = *(const bf16x8*)(ks + 8);
        bf16x8 v1 = *(const bf16x8*)(vs);
        bf16x8 v2 = *(const bf16x8*)(vs + 8);
        *(bf16x8*)&Ks[0][sr][sc]     = k1;
        *(bf16x8*)&Ks[0][sr][sc + 8] = k2;
#pragma unroll
        for (int u = 0; u < 8; ++u) {
            Vt[0][sc + u    ][(kb ^ ((u >> 1) & 7)) * 8 + ko]       = v1[u];
            Vt[0][sc + 8 + u][(kb ^ (((u + 8) >> 1) & 7)) * 8 + ko] = v2[u];
        }
    }
    __syncthreads();

    float m = -1e30f;
    float l[4] = {0.f, 0.f, 0.f, 0.f};
    f32x4 oacc[4];
#pragma unroll
    for (int n = 0; n < 4; ++n)
#pragma unroll
        for (int r = 0; r < 4; ++r) oacc[n][r] = 0.f;

    for (int kt = 0; kt <= qt; ++kt) {
        const int cur = kt & 1;
        const bool pre = (kt < qt);

        // ---- prefetch next K/V tile into regs (latency overlaps compute) ----
        bf16x8 k1, k2, v1, v2;
        if (pre) {
            const __bf16* ks = Kb + (size_t)(kt + 1) * 4096 + sr * 64 + sc;
            const __bf16* vs = Vb + (size_t)(kt + 1) * 4096 + sr * 64 + sc;
            k1 = *(const bf16x8*)(ks);
            k2 = *(const bf16x8*)(ks + 8);
            v1 = *(const bf16x8*)(vs);
            v2 = *(const bf16x8*)(vs + 8);
        }

        // ---- S = Q.K^T ----
        f32x4 sacc[4];
#pragma unroll
        for (int n = 0; n < 4; ++n)
#pragma unroll
            for (int r = 0; r < 4; ++r) sacc[n][r] = 0.f;
#pragma unroll
        for (int kk = 0; kk < 2; ++kk) {
#pragma unroll
            for (int n = 0; n < 4; ++n) {
                bf16x8 bk = *(const bf16x8*)&Ks[cur][n * 16 + lt][kk * 32 + quad * 8];
                sacc[n] = __builtin_amdgcn_mfma_f32_16x16x32_bf16(qf[kk], bk, sacc[n], 0, 0, 0);
            }
        }

        if (kt == qt) {
            const int lq = w * 16 + quad * 4;
#pragma unroll
            for (int n = 0; n < 4; ++n) {
                const int col = n * 16 + lt;
#pragma unroll
                for (int r = 0; r < 4; ++r)
                    if (col > lq + r) sacc[n][r] = -1e30f;
            }
        }

        // ---- strip-wide online softmax ----
        float lm = sacc[0][0];
#pragma unroll
        for (int n = 0; n < 4; ++n)
#pragma unroll
            for (int r = 0; r < 4; ++r) lm = fmaxf(lm, sacc[n][r]);
#pragma unroll
        for (int d = 1; d < 64; d <<= 1) lm = fmaxf(lm, __shfl_xor(lm, d));
        const float mn = fmaxf(m, lm);
        {
            int need = (mn > m) ? 1 : 0;
            need = __builtin_amdgcn_readfirstlane(need);
            if (need) {
                const float al = __expf(m - mn);
#pragma unroll
                for (int r = 0; r < 4; ++r) l[r] *= al;
#pragma unroll
                for (int n = 0; n < 4; ++n)
#pragma unroll
                    for (int r = 0; r < 4; ++r) oacc[n][r] *= al;
            }
            m = mn;
        }

#pragma unroll
        for (int r = 0; r < 4; ++r) {
            const int prow = quad * 4 + r;
            float rs = 0.f;
#pragma unroll
            for (int n = 0; n < 4; ++n) {
                const float p = __expf(sacc[n][r] - m);
                rs += p;
                const int col = n * 16 + lt;
                Ps[w][prow][swz_blk(prow, col >> 3) * 8 + (col & 7)] = (__bf16)p;
            }
            rs += __shfl_xor(rs, 1);
            rs += __shfl_xor(rs, 2);
            rs += __shfl_xor(rs, 4);
            rs += __shfl_xor(rs, 8);
            l[r] += rs;
        }

        // ---- PV (same-wave Ps round-trip) ----
#pragma unroll
        for (int kk = 0; kk < 2; ++kk) {
            bf16x8 ap = *(const bf16x8*)&Ps[w][lt][swz_blk(lt, kk * 4 + quad) * 8];
#pragma unroll
            for (int nd = 0; nd < 4; ++nd) {
                const int drow = nd * 16 + lt;
                bf16x8 bv = *(const bf16x8*)&Vt[cur][drow][swz_blk(drow, kk * 4 + quad) * 8];
                oacc[nd] = __builtin_amdgcn_mfma_f32_16x16x32_bf16(ap, bv, oacc[nd], 0, 0, 0);
            }
        }

        // ---- write prefetched tile into the other buffer; ONE barrier ----
        if (pre) {
            const int nxt = 1 - cur;
            *(bf16x8*)&Ks[nxt][sr][sc]     = k1;
            *(bf16x8*)&Ks[nxt][sr][sc + 8] = k2;
#pragma unroll
            for (int u = 0; u < 8; ++u) {
                Vt[nxt][sc + u    ][(kb ^ ((u >> 1) & 7)) * 8 + ko]       = v1[u];
                Vt[nxt][sc + 8 + u][(kb ^ (((u + 8) >> 1) & 7)) * 8 + ko] = v2[u];
            }
        }
        __syncthreads();
    }

    // ---- epilogue ----
    const float a = fminf(fmaxf(rwr_alpha[h], 0.f), 0.5f);
#pragma unroll
    for (int r = 0; r < 4; ++r) {
        const float inv = 1.f / l[r];
        const int qg = qt * 64 + w * 16 + quad * 4 + r;
        const __bf16* vp = Vb + (size_t)qg * D_;
        __bf16* yp = Y + ((size_t)(b * T_ + qg)) * C_ + h * D_;
#pragma unroll
        for (int nd = 0; nd < 4; ++nd) {
            const int d = nd * 16 + lt;
            yp[d] = (__bf16)((1.f - a) * oacc[nd][r] * inv + a * (float)vp[d]);
        }
    }
}

extern "C" void kernel_launch(void* const* d_in, const int* in_sizes, int n_in,
                              void* d_out, int out_size, void* d_ws, size_t ws_size,
                              hipStream_t stream) {
    const float* x        = (const float*)d_in[0];
    const float* W_attn   = (const float*)d_in[1];
    const float* W_proj   = (const float*)d_in[2];
    const float* w_std    = (const float*)d_in[3];
    const float* w_rec    = (const float*)d_in[4];
    const float* skip_std = (const float*)d_in[5];
    const float* skip_low = (const float*)d_in[6];
    const float* rwr      = (const float*)d_in[7];
    float* out = (float*)d_out;

    const size_t nX  = (size_t)BT_ * C_;
    const size_t nWa = (size_t)F_ * C_;
    const size_t nWp = (size_t)C_ * C_;
    const size_t per = (size_t)B_ * H_ * T_ * D_;

    __bf16* xb  = (__bf16*)d_ws;
    __bf16* Wab = xb  + nX;
    __bf16* Wpb = Wab + nWa;
    __bf16* Qb  = Wpb + nWp;
    __bf16* Kb  = Qb  + per;
    __bf16* Vb  = Kb  + per;
    __bf16* Yb  = Vb  + per;

    cast_kernel<<<dim3((nX  / 4 + 255) / 256), 256, 0, stream>>>(x,      xb,  nX  / 4);
    cast_kernel<<<dim3((nWa / 4 + 255) / 256), 256, 0, stream>>>(W_attn, Wab, nWa / 4);
    cast_kernel<<<dim3((nWp / 4 + 255) / 256), 256, 0, stream>>>(W_proj, Wpb, nWp / 4);

    gemm_qkv_kernel<<<dim3(BT_ / 128, F_ / 128), 256, 0, stream>>>(
        xb, Wab, w_std, w_rec, skip_std, skip_low, Qb, Kb, Vb);
    attn_kernel<<<dim3(32 * (T_ / 64)), 256, 0, stream>>>(Qb, Kb, Vb, rwr, Yb);
    gemm_out_kernel<<<dim3(BT_ / 128, C_ / 128), 256, 0, stream>>>(Yb, Wpb, out);
}

// Round 5
// 195.019 us; speedup vs baseline: 19.3931x; 1.0907x over previous
//
#include <hip/hip_runtime.h>
#include <hip/hip_bf16.h>
#include <math.h>
#include <stdint.h>

#define B_    2
#define T_    2048
#define C_    1024
#define H_    16
#define D_    64
#define R_    4
#define DSTD  60
#define F_    3072
#define BT_   (B_ * T_)

typedef __bf16 bf16x8 __attribute__((ext_vector_type(8)));
typedef __bf16 bf16x4 __attribute__((ext_vector_type(4)));
typedef float  f32x4  __attribute__((ext_vector_type(4)));

// per-row XOR swizzle of 8-element column blocks (unpadded 64-col rows).
// Row stride = 128B = 32 banks, so rows alone never rotate banks; the swizzle
// provides the entropy while keeping b128 reads contiguous.
__device__ __forceinline__ int swz(int row, int blk) {
    return blk ^ ((row >> 1) & 7);
}

__device__ __forceinline__ void st_pair(__bf16* p, __bf16 a, __bf16 b) {
    union { __bf16 h[2]; uint32_t u; } t;
    t.h[0] = a; t.h[1] = b;
    *(uint32_t*)p = t.u;
}

// async global->LDS, 16B per lane. LDS dest MUST be wave-uniform base + lane*16.
__device__ __forceinline__ void gload_lds16(const void* g, void* l) {
    __builtin_amdgcn_global_load_lds(
        (const __attribute__((address_space(1))) uint32_t*)g,
        (__attribute__((address_space(3))) uint32_t*)l, 16, 0, 0);
}

// ---------------------------------------------------------------------------
// fused fp32 -> bf16 cast of x, W_attn, W_proj (one launch)
// ---------------------------------------------------------------------------
__global__ __launch_bounds__(256) void cast3_kernel(
    const float* __restrict__ a, int na4,
    const float* __restrict__ b, int nb4,
    const float* __restrict__ c, int nc4,
    __bf16* __restrict__ oa, __bf16* __restrict__ ob, __bf16* __restrict__ oc)
{
    int i = blockIdx.x * 256 + threadIdx.x;
    const float* s; __bf16* d; int j = i;
    if (j < na4) { s = a; d = oa; }
    else {
        j -= na4;
        if (j < nb4) { s = b; d = ob; }
        else {
            j -= nb4;
            if (j >= nc4) return;
            s = c; d = oc;
        }
    }
    float4 v = ((const float4*)s)[j];
    bf16x4 o;
    o[0] = (__bf16)v.x; o[1] = (__bf16)v.y;
    o[2] = (__bf16)v.z; o[3] = (__bf16)v.w;
    ((bf16x4*)d)[j] = o;
}

// ---------------------------------------------------------------------------
// m97-style bf16 MFMA GEMM: out = A(M,K) @ B(N,K)^T. 128x128 tile, 256 thr.
// GEMM1 epilogue: scale q/k, scatter bf16 into (B,H,T,D) Q/K/V.
// ---------------------------------------------------------------------------
__global__ __launch_bounds__(256) void gemm_qkv_kernel(
    const __bf16* __restrict__ A,    // x   (BT, C) bf16
    const __bf16* __restrict__ Bw,   // Wa  (F,  C) bf16
    const float* __restrict__ w_std, const float* __restrict__ w_rec,
    const float* __restrict__ skip_std, const float* __restrict__ skip_low,
    __bf16* __restrict__ Q, __bf16* __restrict__ K, __bf16* __restrict__ V)
{
    __shared__ __bf16 As[128 * 32];
    __shared__ __bf16 Bs[128 * 32];

    const int tid  = threadIdx.x;
    const int row0 = blockIdx.x * 128;
    const int col0 = blockIdx.y * 128;

    const int w    = tid >> 6;
    const int lane = tid & 63;
    const int quad = lane >> 4;
    const int lt   = lane & 15;
    const int wm   = w >> 1;
    const int wn   = w & 1;

    const int lrow = tid >> 2;
    const int lcol = (tid & 3) * 8;

    f32x4 acc[4][4];
#pragma unroll
    for (int i = 0; i < 4; ++i)
#pragma unroll
        for (int j = 0; j < 4; ++j)
#pragma unroll
            for (int r = 0; r < 4; ++r) acc[i][j][r] = 0.f;

    for (int kt = 0; kt < C_ / 32; ++kt) {
        const int k0 = kt * 32;
        __syncthreads();
#pragma unroll
        for (int rr = 0; rr < 2; ++rr) {
            gload_lds16(A  + (size_t)(row0 + rr * 64 + lrow) * C_ + k0 + lcol,
                        As + rr * 2048 + tid * 8);
            gload_lds16(Bw + (size_t)(col0 + rr * 64 + lrow) * C_ + k0 + lcol,
                        Bs + rr * 2048 + tid * 8);
        }
        __syncthreads();

        bf16x8 af[4], bf[4];
#pragma unroll
        for (int i = 0; i < 4; ++i)
            af[i] = *(const bf16x8*)&As[(wm * 64 + i * 16 + lt) * 32 + quad * 8];
#pragma unroll
        for (int j = 0; j < 4; ++j)
            bf[j] = *(const bf16x8*)&Bs[(wn * 64 + j * 16 + lt) * 32 + quad * 8];
#pragma unroll
        for (int i = 0; i < 4; ++i)
#pragma unroll
            for (int j = 0; j < 4; ++j)
                acc[i][j] = __builtin_amdgcn_mfma_f32_16x16x32_bf16(af[i], bf[j], acc[i][j], 0, 0, 0);
    }

    const int colbase = col0 + wn * 64;
    const int which   = colbase >> 10;
    const int h       = (colbase & (C_ - 1)) >> 6;

    const float ss = 1.f / (1.f + __expf(-skip_std[0]));
    const float sl = 1.f / (1.f + __expf(-skip_low[0]));
    const float gs = sqrtf(fmaxf(w_std[h] * ss, 1e-8f));
    const float gr = sqrtf(fmaxf(w_rec[h] * sl, 1e-8f));

    __bf16* dstM = (which == 0) ? Q : (which == 1) ? K : V;

#pragma unroll
    for (int i = 0; i < 4; ++i) {
#pragma unroll
        for (int r = 0; r < 4; ++r) {
            const int row = row0 + wm * 64 + i * 16 + quad * 4 + r;
            const int b = row >> 11;
            const int t = row & (T_ - 1);
            __bf16* dp = dstM + (((size_t)b * H_ + h) * T_ + t) * D_;
#pragma unroll
            for (int j = 0; j < 4; ++j) {
                const int d = j * 16 + lt;
                float val = acc[i][j][r];
                if (which == 0)      val *= ((d < DSTD) ? gs : gr) * 0.125f;
                else if (which == 1) val *= (d < DSTD) ? gs : gr;
                dp[d] = (__bf16)val;
            }
        }
    }
}

// ---------------------------------------------------------------------------
// GEMM2: out = Y(BT,C) @ Wp(C,C)^T, fp32 out.
// ---------------------------------------------------------------------------
__global__ __launch_bounds__(256) void gemm_out_kernel(
    const __bf16* __restrict__ A,
    const __bf16* __restrict__ Bw,
    float* __restrict__ out)
{
    __shared__ __bf16 As[128 * 32];
    __shared__ __bf16 Bs[128 * 32];

    const int tid  = threadIdx.x;
    const int row0 = blockIdx.x * 128;
    const int col0 = blockIdx.y * 128;

    const int w    = tid >> 6;
    const int lane = tid & 63;
    const int quad = lane >> 4;
    const int lt   = lane & 15;
    const int wm   = w >> 1;
    const int wn   = w & 1;

    const int lrow = tid >> 2;
    const int lcol = (tid & 3) * 8;

    f32x4 acc[4][4];
#pragma unroll
    for (int i = 0; i < 4; ++i)
#pragma unroll
        for (int j = 0; j < 4; ++j)
#pragma unroll
            for (int r = 0; r < 4; ++r) acc[i][j][r] = 0.f;

    for (int kt = 0; kt < C_ / 32; ++kt) {
        const int k0 = kt * 32;
        __syncthreads();
#pragma unroll
        for (int rr = 0; rr < 2; ++rr) {
            gload_lds16(A  + (size_t)(row0 + rr * 64 + lrow) * C_ + k0 + lcol,
                        As + rr * 2048 + tid * 8);
            gload_lds16(Bw + (size_t)(col0 + rr * 64 + lrow) * C_ + k0 + lcol,
                        Bs + rr * 2048 + tid * 8);
        }
        __syncthreads();

        bf16x8 af[4], bf[4];
#pragma unroll
        for (int i = 0; i < 4; ++i)
            af[i] = *(const bf16x8*)&As[(wm * 64 + i * 16 + lt) * 32 + quad * 8];
#pragma unroll
        for (int j = 0; j < 4; ++j)
            bf[j] = *(const bf16x8*)&Bs[(wn * 64 + j * 16 + lt) * 32 + quad * 8];
#pragma unroll
        for (int i = 0; i < 4; ++i)
#pragma unroll
            for (int j = 0; j < 4; ++j)
                acc[i][j] = __builtin_amdgcn_mfma_f32_16x16x32_bf16(af[i], bf[j], acc[i][j], 0, 0, 0);
    }

#pragma unroll
    for (int i = 0; i < 4; ++i)
#pragma unroll
        for (int r = 0; r < 4; ++r) {
            const int row = row0 + wm * 64 + i * 16 + quad * 4 + r;
            float* op = out + (size_t)row * C_ + col0 + wn * 64 + lt;
#pragma unroll
            for (int j = 0; j < 4; ++j)
                op[j * 16] = acc[i][j][r];
        }
}

// ---------------------------------------------------------------------------
// MFMA flash attention, R4: unpadded swizzled LDS (40KB -> 4 blocks/CU),
// pair-packed Vt staging (b32 transposed writes), epilogue-deferred l-sum,
// LPT dispatch, reg-prefetch double-buffer, one barrier/iter.
// ---------------------------------------------------------------------------
__global__ __launch_bounds__(256) void attn_kernel(
    const __bf16* __restrict__ Q, const __bf16* __restrict__ K,
    const __bf16* __restrict__ V, const float* __restrict__ rwr_alpha,
    __bf16* __restrict__ Y)   // (B,T,C) bf16
{
    __shared__ __align__(16) __bf16 Ks[2][64][64];
    __shared__ __align__(16) __bf16 Vt[2][64][64];   // Vt[d][key], swizzled
    __shared__ __align__(16) __bf16 Ps[4][16][64];   // per-wave P strip, swizzled

    const int tid = threadIdx.x;
    const int nqt = T_ / 64;                       // 32
    const int bh  = blockIdx.x & 31;               // b*H + h
    const int qt  = nqt - 1 - (blockIdx.x >> 5);   // LPT: heavy blocks first
    const int h   = bh & (H_ - 1);
    const int b   = bh >> 4;

    const __bf16* Qb = Q + (((size_t)b * H_ + h) * T_) * D_;
    const __bf16* Kb = K + (((size_t)b * H_ + h) * T_) * D_;
    const __bf16* Vb = V + (((size_t)b * H_ + h) * T_) * D_;

    const int w    = tid >> 6;
    const int lane = tid & 63;
    const int quad = lane >> 4;
    const int lt   = lane & 15;

    // staging assignment: 2 adjacent keys x 8 d per thread
    const int kp = (tid >> 3) * 2;        // even key (0..62)
    const int dc = (tid & 7) * 8;         // d col base
    const int kblk = kp >> 3, koff = kp & 7;

    // ---- Q A-frags direct from global ----
    const __bf16* qrow = Qb + (size_t)(qt * 64 + w * 16 + lt) * D_;
    bf16x8 qf[2];
    qf[0] = *(const bf16x8*)(qrow + quad * 8);
    qf[1] = *(const bf16x8*)(qrow + 32 + quad * 8);

    // ---- stage tile 0 into buffer 0 ----
    {
        const __bf16* ks = Kb + (size_t)kp * 64 + dc;
        const __bf16* vs = Vb + (size_t)kp * 64 + dc;
        bf16x8 k1 = *(const bf16x8*)(ks);
        bf16x8 k2 = *(const bf16x8*)(ks + 64);
        bf16x8 v1 = *(const bf16x8*)(vs);
        bf16x8 v2 = *(const bf16x8*)(vs + 64);
        *(bf16x8*)&Ks[0][kp    ][swz(kp, dc >> 3) * 8] = k1;
        *(bf16x8*)&Ks[0][kp + 1][swz(kp, dc >> 3) * 8] = k2;   // (kp+1)>>1 == kp>>1
#pragma unroll
        for (int u = 0; u < 8; ++u) {
            const int row = dc + u;
            st_pair(&Vt[0][row][swz(row, kblk) * 8 + koff], v1[u], v2[u]);
        }
    }
    __syncthreads();

    float m = -1e30f;
    float l[4] = {0.f, 0.f, 0.f, 0.f};   // per-lane partials; reduced in epilogue
    f32x4 oacc[4];
#pragma unroll
    for (int n = 0; n < 4; ++n)
#pragma unroll
        for (int r = 0; r < 4; ++r) oacc[n][r] = 0.f;

    for (int kt = 0; kt <= qt; ++kt) {
        const int cur = kt & 1;
        const bool pre = (kt < qt);

        // ---- prefetch next K/V tile into regs ----
        bf16x8 k1, k2, v1, v2;
        if (pre) {
            const __bf16* ks = Kb + (size_t)(kt + 1) * 4096 + (size_t)kp * 64 + dc;
            const __bf16* vs = Vb + (size_t)(kt + 1) * 4096 + (size_t)kp * 64 + dc;
            k1 = *(const bf16x8*)(ks);
            k2 = *(const bf16x8*)(ks + 64);
            v1 = *(const bf16x8*)(vs);
            v2 = *(const bf16x8*)(vs + 64);
        }

        // ---- S = Q.K^T ----
        f32x4 sacc[4];
#pragma unroll
        for (int n = 0; n < 4; ++n)
#pragma unroll
            for (int r = 0; r < 4; ++r) sacc[n][r] = 0.f;
#pragma unroll
        for (int kk = 0; kk < 2; ++kk) {
#pragma unroll
            for (int n = 0; n < 4; ++n) {
                const int row = n * 16 + lt;
                bf16x8 bk = *(const bf16x8*)&Ks[cur][row][swz(row, kk * 4 + quad) * 8];
                sacc[n] = __builtin_amdgcn_mfma_f32_16x16x32_bf16(qf[kk], bk, sacc[n], 0, 0, 0);
            }
        }

        if (kt == qt) {
            const int lq = w * 16 + quad * 4;
#pragma unroll
            for (int n = 0; n < 4; ++n) {
                const int col = n * 16 + lt;
#pragma unroll
                for (int r = 0; r < 4; ++r)
                    if (col > lq + r) sacc[n][r] = -1e30f;
            }
        }

        // ---- strip-wide online softmax ----
        float lm = sacc[0][0];
#pragma unroll
        for (int n = 0; n < 4; ++n)
#pragma unroll
            for (int r = 0; r < 4; ++r) lm = fmaxf(lm, sacc[n][r]);
#pragma unroll
        for (int d = 1; d < 64; d <<= 1) lm = fmaxf(lm, __shfl_xor(lm, d));
        const float mn = fmaxf(m, lm);
        {
            int need = (mn > m) ? 1 : 0;
            need = __builtin_amdgcn_readfirstlane(need);
            if (need) {
                const float al = __expf(m - mn);
#pragma unroll
                for (int r = 0; r < 4; ++r) l[r] *= al;
#pragma unroll
                for (int n = 0; n < 4; ++n)
#pragma unroll
                    for (int r = 0; r < 4; ++r) oacc[n][r] *= al;
            }
            m = mn;
        }

        // ---- exp + P write (l stays per-lane partial) ----
#pragma unroll
        for (int r = 0; r < 4; ++r) {
            const int prow = quad * 4 + r;
#pragma unroll
            for (int n = 0; n < 4; ++n) {
                const float p = __expf(sacc[n][r] - m);
                l[r] += p;
                Ps[w][prow][swz(prow, n * 2 + (lt >> 3)) * 8 + (lt & 7)] = (__bf16)p;
            }
        }

        // ---- PV (same-wave Ps round-trip) ----
#pragma unroll
        for (int kk = 0; kk < 2; ++kk) {
            bf16x8 ap = *(const bf16x8*)&Ps[w][lt][swz(lt, kk * 4 + quad) * 8];
#pragma unroll
            for (int nd = 0; nd < 4; ++nd) {
                const int drow = nd * 16 + lt;
                bf16x8 bv = *(const bf16x8*)&Vt[cur][drow][swz(drow, kk * 4 + quad) * 8];
                oacc[nd] = __builtin_amdgcn_mfma_f32_16x16x32_bf16(ap, bv, oacc[nd], 0, 0, 0);
            }
        }

        // ---- write prefetched tile into the other buffer; ONE barrier ----
        if (pre) {
            const int nxt = 1 - cur;
            *(bf16x8*)&Ks[nxt][kp    ][swz(kp, dc >> 3) * 8] = k1;
            *(bf16x8*)&Ks[nxt][kp + 1][swz(kp, dc >> 3) * 8] = k2;
#pragma unroll
            for (int u = 0; u < 8; ++u) {
                const int row = dc + u;
                st_pair(&Vt[nxt][row][swz(row, kblk) * 8 + koff], v1[u], v2[u]);
            }
        }
        __syncthreads();
    }

    // ---- epilogue: reduce l across the 16 lanes of the quad, normalize ----
    const float a = fminf(fmaxf(rwr_alpha[h], 0.f), 0.5f);
#pragma unroll
    for (int r = 0; r < 4; ++r) {
        float lr = l[r];
        lr += __shfl_xor(lr, 1);
        lr += __shfl_xor(lr, 2);
        lr += __shfl_xor(lr, 4);
        lr += __shfl_xor(lr, 8);
        const float inv = 1.f / lr;
        const int qg = qt * 64 + w * 16 + quad * 4 + r;
        const __bf16* vp = Vb + (size_t)qg * D_;
        __bf16* yp = Y + ((size_t)(b * T_ + qg)) * C_ + h * D_;
#pragma unroll
        for (int nd = 0; nd < 4; ++nd) {
            const int d = nd * 16 + lt;
            yp[d] = (__bf16)((1.f - a) * oacc[nd][r] * inv + a * (float)vp[d]);
        }
    }
}

extern "C" void kernel_launch(void* const* d_in, const int* in_sizes, int n_in,
                              void* d_out, int out_size, void* d_ws, size_t ws_size,
                              hipStream_t stream) {
    const float* x        = (const float*)d_in[0];
    const float* W_attn   = (const float*)d_in[1];
    const float* W_proj   = (const float*)d_in[2];
    const float* w_std    = (const float*)d_in[3];
    const float* w_rec    = (const float*)d_in[4];
    const float* skip_std = (const float*)d_in[5];
    const float* skip_low = (const float*)d_in[6];
    const float* rwr      = (const float*)d_in[7];
    float* out = (float*)d_out;

    const size_t nX  = (size_t)BT_ * C_;
    const size_t nWa = (size_t)F_ * C_;
    const size_t nWp = (size_t)C_ * C_;
    const size_t per = (size_t)B_ * H_ * T_ * D_;

    __bf16* xb  = (__bf16*)d_ws;
    __bf16* Wab = xb  + nX;
    __bf16* Wpb = Wab + nWa;
    __bf16* Qb  = Wpb + nWp;
    __bf16* Kb  = Qb  + per;
    __bf16* Vb  = Kb  + per;
    __bf16* Yb  = Vb  + per;

    const int na4 = nX / 4, nb4 = nWa / 4, nc4 = nWp / 4;
    cast3_kernel<<<dim3((na4 + nb4 + nc4 + 255) / 256), 256, 0, stream>>>(
        x, na4, W_attn, nb4, W_proj, nc4, xb, Wab, Wpb);

    gemm_qkv_kernel<<<dim3(BT_ / 128, F_ / 128), 256, 0, stream>>>(
        xb, Wab, w_std, w_rec, skip_std, skip_low, Qb, Kb, Vb);
    attn_kernel<<<dim3(32 * (T_ / 64)), 256, 0, stream>>>(Qb, Kb, Vb, rwr, Yb);
    gemm_out_kernel<<<dim3(BT_ / 128, C_ / 128), 256, 0, stream>>>(Yb, Wpb, out);
}